// Round 2
// baseline (289.915 us; speedup 1.0000x reference)
//
#include <hip/hip_runtime.h>

// OWA pooling: 3x3 window, stride 2, pad bottom/right by 1 (zeros),
// sort 9 window values descending per channel, weighted sum with kernel[9][64].
//
// Input : (16, 224, 224, 64) fp32, NHWC
// Kernel: (9, 64) fp32
// Output: (16, 112, 112, 64) fp32
//
// R2: 1x2 output pixels/thread (15 shared window loads), weights staged in
// LDS, XCD-contiguous block swizzle so input-row reuse hits the local L2.

#define BB 16
#define HH 224
#define WW 224
#define CC 64
#define PH 112
#define PW 112
#define ROWSTRIDE (WW * CC)   // 14336 floats per input row

__device__ __forceinline__ void ce(float4& a, float4& b) {
    float4 lo, hi;
    lo.x = fminf(a.x, b.x); hi.x = fmaxf(a.x, b.x);
    lo.y = fminf(a.y, b.y); hi.y = fmaxf(a.y, b.y);
    lo.z = fminf(a.z, b.z); hi.z = fmaxf(a.z, b.z);
    lo.w = fminf(a.w, b.w); hi.w = fmaxf(a.w, b.w);
    a = lo; b = hi;
}

__device__ __forceinline__ void sort9(float4 s[9]) {
    // optimal 25-CE network, ascending
    ce(s[0], s[3]); ce(s[1], s[7]); ce(s[2], s[5]); ce(s[4], s[8]);
    ce(s[0], s[7]); ce(s[2], s[4]); ce(s[3], s[8]); ce(s[5], s[6]);
    ce(s[0], s[2]); ce(s[1], s[3]); ce(s[4], s[5]); ce(s[7], s[8]);
    ce(s[1], s[4]); ce(s[3], s[6]); ce(s[5], s[7]);
    ce(s[0], s[1]); ce(s[2], s[4]); ce(s[3], s[5]); ce(s[6], s[8]);
    ce(s[2], s[3]); ce(s[4], s[5]); ce(s[6], s[7]);
    ce(s[1], s[2]); ce(s[3], s[4]); ce(s[5], s[6]);
}

__device__ __forceinline__ float4 ld4(const float* p) {
    return *reinterpret_cast<const float4*>(p);
}

// grid = 16*112*56*16 / 256 = 6272 blocks = 8 * 784
#define NBLK 6272
#define BLK_PER_XCD (NBLK / 8)

__global__ __launch_bounds__(256) void owa_pool_kernel(
    const float* __restrict__ in, const float* __restrict__ kw,
    float* __restrict__ out) {
    __shared__ float ksh[9 * CC];
    for (int i = threadIdx.x; i < 9 * CC; i += 256) ksh[i] = kw[i];
    __syncthreads();

    // XCD-contiguous swizzle: physical block p -> XCD p%8 (heuristic);
    // give each XCD a contiguous slab of logical work for L2 row reuse.
    int bid = blockIdx.x;
    int lb  = (bid & 7) * BLK_PER_XCD + (bid >> 3);

    int idx  = lb * 256 + threadIdx.x;
    int cg   = idx & 15;          // channel group (4 channels)
    int rest = idx >> 4;
    int owp  = rest % (PW / 2);   // output-pixel pair index (0..55)
    int t    = rest / (PW / 2);
    int oh   = t % PH;
    int b    = t / PH;

    int c0  = cg * 4;
    int ih0 = oh * 2;
    int iw0 = owp * 4;            // first input column of the 5-col span

    const float* pr0 = in + ((long)(b * HH + ih0) * WW + iw0) * CC + c0;
    const float* pr1 = pr0 + ROWSTRIDE;
    const float* pr2 = pr1 + ROWSTRIDE;

    bool r2ok = (ih0 + 2) < HH;   // false only for oh == 111
    bool c4ok = (iw0 + 4) < WW;   // false only for owp == 55

    const float4 Z = make_float4(0.f, 0.f, 0.f, 0.f);
    float4 v[3][5];
#pragma unroll
    for (int k = 0; k < 4; ++k) {
        v[0][k] = ld4(pr0 + k * CC);
        v[1][k] = ld4(pr1 + k * CC);
    }
    v[0][4] = c4ok ? ld4(pr0 + 4 * CC) : Z;
    v[1][4] = c4ok ? ld4(pr1 + 4 * CC) : Z;
    if (r2ok) {
#pragma unroll
        for (int k = 0; k < 4; ++k) v[2][k] = ld4(pr2 + k * CC);
        v[2][4] = c4ok ? ld4(pr2 + 4 * CC) : Z;
    } else {
#pragma unroll
        for (int k = 0; k < 5; ++k) v[2][k] = Z;
    }

    long obase = ((long)(b * PH + oh) * PW + owp * 2) * CC + c0;

    // ---- output A: window cols 0,1,2 ----
    {
        float4 s[9];
#pragma unroll
        for (int r = 0; r < 3; ++r) {
            s[r * 3 + 0] = v[r][0];
            s[r * 3 + 1] = v[r][1];
            s[r * 3 + 2] = v[r][2];
        }
        sort9(s);
        float4 acc = Z;
#pragma unroll
        for (int k = 0; k < 9; ++k) {
            float4 w = *reinterpret_cast<const float4*>(&ksh[(8 - k) * CC + c0]);
            acc.x += s[k].x * w.x;
            acc.y += s[k].y * w.y;
            acc.z += s[k].z * w.z;
            acc.w += s[k].w * w.w;
        }
        *reinterpret_cast<float4*>(out + obase) = acc;
    }

    // ---- output B: window cols 2,3,4 ----
    {
        float4 s[9];
#pragma unroll
        for (int r = 0; r < 3; ++r) {
            s[r * 3 + 0] = v[r][2];
            s[r * 3 + 1] = v[r][3];
            s[r * 3 + 2] = v[r][4];
        }
        sort9(s);
        float4 acc = Z;
#pragma unroll
        for (int k = 0; k < 9; ++k) {
            float4 w = *reinterpret_cast<const float4*>(&ksh[(8 - k) * CC + c0]);
            acc.x += s[k].x * w.x;
            acc.y += s[k].y * w.y;
            acc.z += s[k].z * w.z;
            acc.w += s[k].w * w.w;
        }
        *reinterpret_cast<float4*>(out + obase + CC) = acc;
    }
}

extern "C" void kernel_launch(void* const* d_in, const int* in_sizes, int n_in,
                              void* d_out, int out_size, void* d_ws, size_t ws_size,
                              hipStream_t stream) {
    const float* in = (const float*)d_in[0];
    const float* kw = (const float*)d_in[1];
    float* out = (float*)d_out;

    owa_pool_kernel<<<NBLK, 256, 0, stream>>>(in, kw, out);
}